// Round 1
// baseline (548.970 us; speedup 1.0000x reference)
//
#include <hip/hip_runtime.h>

typedef __attribute__((ext_vector_type(8))) short bf16x8;
typedef __attribute__((ext_vector_type(4))) float f32x4;

#if defined(__has_builtin)
#if __has_builtin(__builtin_amdgcn_global_load_lds)
#define HAVE_GLL 1
#endif
#endif

__device__ __forceinline__ ushort f2bf(float f) {
    unsigned u = __float_as_uint(f);
    u += 0x7fffu + ((u >> 16) & 1u);   // round-to-nearest-even
    return (ushort)(u >> 16);
}

// global->LDS 16B stage. GLL path: lbase is wave-uniform, HW adds lane*16.
__device__ __forceinline__ void stage16(const ushort* __restrict__ g, ushort* lbase, int lane) {
#ifdef HAVE_GLL
    __builtin_amdgcn_global_load_lds((const __attribute__((address_space(1))) void*)g,
                                     (__attribute__((address_space(3))) void*)lbase,
                                     16, 0, 0);
#else
    *(float4*)(lbase + lane * 8) = *(const float4*)g;
#endif
}

// ---------------- K0: f32 -> bf16 weight conversion ----------------
__global__ void k_cvt(const float* __restrict__ src, ushort* __restrict__ dst, int n4) {
    int i = blockIdx.x * blockDim.x + threadIdx.x;
    if (i >= n4) return;
    float4 v = ((const float4*)src)[i];
    ushort4 o;
    o.x = f2bf(v.x); o.y = f2bf(v.y); o.z = f2bf(v.z); o.w = f2bf(v.w);
    ((ushort4*)dst)[i] = o;
}

// ---------------- K1: per-row stats + params + layer_input ----------------
// block = 512 threads (8 waves), 32 rows/block, grid = 256.
// Waves: kh = wv>>2 (K-half), mt = wv&1 (row half), jt = (wv>>1)&1 (proj half).
__global__ __launch_bounds__(512) void k_stats(
    const float* __restrict__ x,        // [8192][8192]
    const ushort* __restrict__ wallb,   // [32][8192] bf16
    const float* __restrict__ b_all,    // [32]
    const float* __restrict__ a_pre, const float* __restrict__ a_post,
    const float* __restrict__ a_res,
    const float* __restrict__ perm,     // [24][16]
    float* __restrict__ params,         // [8192][24]: h_pre[4] h_post[4] Hm[16]
    ushort* __restrict__ li)            // [8192][2048] bf16
{
    __shared__ ushort Alds[2][32 * 64];
    __shared__ ushort Blds[2][32 * 64];
    __shared__ float dots_s[2][32][33];
    __shared__ float ssq_l[512];
    __shared__ float hpre_l[32][4];

    const int tid = threadIdx.x;
    const int lane = tid & 63;
    const int wv = tid >> 6;
    const int brow = blockIdx.x * 32;

    const int kh = tid >> 8;       // staging K-half
    const int h = tid & 255;
    const int sr = h >> 3;         // row 0..31 (also W_all row j)
    const int sk = (h & 7) * 8;

    const float* __restrict__ xrow = x + (size_t)(brow + sr) * 8192 + kh * 4096 + sk;
    const ushort* __restrict__ wrow = wallb + (size_t)sr * 8192 + kh * 4096 + sk;

    float4 ra0 = *(const float4*)(xrow);
    float4 ra1 = *(const float4*)(xrow + 4);
    float4 rb = *(const float4*)(wrow);

    const int kh_w = wv >> 2, mt = wv & 1, jt = (wv >> 1) & 1;
    const ushort* Abase = &Alds[kh_w][(mt * 16 + (lane & 15)) * 64 + ((lane >> 4) * 8)];
    const ushort* Bbase = &Blds[kh_w][(jt * 16 + (lane & 15)) * 64 + ((lane >> 4) * 8)];

    f32x4 acc = {0.f, 0.f, 0.f, 0.f};
    float ssq = 0.f;

    for (int step = 0; step < 64; ++step) {
        __syncthreads();
        float va[8] = {ra0.x, ra0.y, ra0.z, ra0.w, ra1.x, ra1.y, ra1.z, ra1.w};
        union { ushort u[8]; float4 f; } pk;
#pragma unroll
        for (int j = 0; j < 8; ++j) { float v = va[j]; ssq += v * v; pk.u[j] = f2bf(v); }
        *(float4*)&Alds[kh][sr * 64 + sk] = pk.f;
        *(float4*)&Blds[kh][sr * 64 + sk] = rb;
        __syncthreads();
        if (step + 1 < 64) {   // prefetch next tile while MFMA runs
            const float* xp = xrow + (step + 1) * 64;
            ra0 = *(const float4*)(xp);
            ra1 = *(const float4*)(xp + 4);
            rb = *(const float4*)(wrow + (step + 1) * 64);
        }
        bf16x8 a0 = *(const bf16x8*)(Abase);
        bf16x8 a1 = *(const bf16x8*)(Abase + 32);
        bf16x8 b0 = *(const bf16x8*)(Bbase);
        bf16x8 b1 = *(const bf16x8*)(Bbase + 32);
        acc = __builtin_amdgcn_mfma_f32_16x16x32_bf16(a0, b0, acc, 0, 0, 0);
        acc = __builtin_amdgcn_mfma_f32_16x16x32_bf16(a1, b1, acc, 0, 0, 0);
    }

#pragma unroll
    for (int i = 0; i < 4; ++i)
        dots_s[kh_w][mt * 16 + (lane >> 4) * 4 + i][jt * 16 + (lane & 15)] = acc[i];
    ssq_l[tid] = ssq;
    __syncthreads();

    if (tid < 32) {   // one thread per row: scalar epilogue
        float s = 0.f;
#pragma unroll
        for (int q = 0; q < 8; ++q) s += ssq_l[tid * 8 + q] + ssq_l[256 + tid * 8 + q];
        float inv_rms = rsqrtf(s * (1.0f / 8192.0f) + 1.1920929e-7f);
        float pj[32];
#pragma unroll
        for (int j = 0; j < 32; ++j)
            pj[j] = (dots_s[0][tid][j] + dots_s[1][tid][j]) * inv_rms;
        float ap = a_pre[0], apo = a_post[0], ar = a_res[0];
        float hpre[4], hpost[4];
#pragma unroll
        for (int n = 0; n < 4; ++n) {
            hpre[n] = 1.0f / (1.0f + expf(-(ap * pj[n] + b_all[n])));
            hpost[n] = 2.0f / (1.0f + expf(-(apo * pj[4 + n] + b_all[4 + n])));
        }
        float z[24]; float mx = -1e30f;
#pragma unroll
        for (int p = 0; p < 24; ++p) { z[p] = ar * pj[8 + p] + b_all[8 + p]; mx = fmaxf(mx, z[p]); }
        float se = 0.f;
#pragma unroll
        for (int p = 0; p < 24; ++p) { z[p] = expf(z[p] - mx); se += z[p]; }
        float isum = 1.0f / se;
        float Hr[16];
#pragma unroll
        for (int e = 0; e < 16; ++e) Hr[e] = 0.f;
#pragma unroll
        for (int p = 0; p < 24; ++p) {
            float a = z[p] * isum;
#pragma unroll
            for (int e = 0; e < 16; ++e) Hr[e] += a * perm[p * 16 + e];
        }
        float* P = params + (size_t)(brow + tid) * 24;
#pragma unroll
        for (int n = 0; n < 4; ++n) { P[n] = hpre[n]; P[4 + n] = hpost[n]; hpre_l[tid][n] = hpre[n]; }
#pragma unroll
        for (int n = 0; n < 4; ++n)
#pragma unroll
            for (int m = 0; m < 4; ++m)
                P[8 + n * 4 + m] = Hr[n * 4 + m] - hpost[n] * hpre[m];
    }
    __syncthreads();

    // layer_input phase: rows hot in L2 from the k-loop
    const int c = tid * 4;
#pragma unroll 4
    for (int r = 0; r < 32; ++r) {
        float h0 = hpre_l[r][0], h1 = hpre_l[r][1], h2 = hpre_l[r][2], h3 = hpre_l[r][3];
        const float* xr = x + (size_t)(brow + r) * 8192 + c;
        float4 a0 = *(const float4*)(xr);
        float4 a1 = *(const float4*)(xr + 2048);
        float4 a2 = *(const float4*)(xr + 4096);
        float4 a3 = *(const float4*)(xr + 6144);
        ushort4 ob;
        ob.x = f2bf(h0 * a0.x + h1 * a1.x + h2 * a2.x + h3 * a3.x);
        ob.y = f2bf(h0 * a0.y + h1 * a1.y + h2 * a2.y + h3 * a3.y);
        ob.z = f2bf(h0 * a0.z + h1 * a1.z + h2 * a2.z + h3 * a3.z);
        ob.w = f2bf(h0 * a0.w + h1 * a1.w + h2 * a2.w + h3 * a3.w);
        *(ushort4*)(li + (size_t)(brow + r) * 2048 + c) = ob;
    }
}

// ---------------- K3: GEMM (li @ W_layer^T) + fused final combine ----------------
// 128x128 tile, BK=64, 4 waves, m97 structure. Epilogue computes d_out directly.
__global__ __launch_bounds__(256) void k_gemm_out(
    const ushort* __restrict__ liA,    // [8192][2048] bf16
    const ushort* __restrict__ WB,     // [2048][2048] bf16 (c,k) = B^T layout
    const float* __restrict__ b_layer, // [2048]
    const float* __restrict__ params,  // [8192][24]
    const float* __restrict__ x,       // [8192][8192]
    float* __restrict__ out)           // [8192][4][2048]
{
    __shared__ ushort Alds[128 * 64];
    __shared__ ushort Blds[128 * 64];
    __shared__ float Plds[128 * 24];
    __shared__ float bl_s[128];

    const int tid = threadIdx.x;
    const int ln = tid & 63;
    const int wv = tid >> 6;
    const int brow = blockIdx.x * 128;
    const int bcol = blockIdx.y * 128;

    for (int i = tid; i < 128 * 24; i += 256) Plds[i] = params[(size_t)brow * 24 + i];
    if (tid < 128) bl_s[tid] = b_layer[bcol + tid];

    f32x4 acc[4][4] = {};

    const int srow = ln >> 3;
    const int scol = (ln & 7) * 8;
    const int wm = wv >> 1, wn = wv & 1;
    const int fr = ln & 15, fq = ln >> 4;

    for (int k0 = 0; k0 < 2048; k0 += 64) {
        __syncthreads();
#pragma unroll
        for (int q = 0; q < 4; ++q) {
            int row = wv * 32 + q * 8 + srow;
            stage16(liA + (size_t)(brow + row) * 2048 + k0 + scol, &Alds[wv * 2048 + q * 512], ln);
            stage16(WB + (size_t)(bcol + row) * 2048 + k0 + scol, &Blds[wv * 2048 + q * 512], ln);
        }
        __syncthreads();
#pragma unroll
        for (int kk = 0; kk < 64; kk += 32) {
            bf16x8 af[4], bg[4];
#pragma unroll
            for (int mi = 0; mi < 4; ++mi)
                af[mi] = *(const bf16x8*)&Alds[(wm * 64 + mi * 16 + fr) * 64 + kk + fq * 8];
#pragma unroll
            for (int ni = 0; ni < 4; ++ni)
                bg[ni] = *(const bf16x8*)&Blds[(wn * 64 + ni * 16 + fr) * 64 + kk + fq * 8];
#pragma unroll
            for (int mi = 0; mi < 4; ++mi)
#pragma unroll
                for (int ni = 0; ni < 4; ++ni)
                    acc[mi][ni] = __builtin_amdgcn_mfma_f32_16x16x32_bf16(af[mi], bg[ni], acc[mi][ni], 0, 0, 0);
        }
    }

    // Epilogue: out[t,n,c] = sum_m Hm[n,m]*x[t,m,c] + h_post[n]*(acc + b_layer[c])
#pragma unroll
    for (int mi = 0; mi < 4; ++mi) {
#pragma unroll
        for (int ni = 0; ni < 4; ++ni) {
            int c_loc = wn * 64 + ni * 16 + fr;
            int cg = bcol + c_loc;
            float bl = bl_s[c_loc];
#pragma unroll
            for (int i = 0; i < 4; ++i) {
                int r_loc = wm * 64 + mi * 16 + fq * 4 + i;
                size_t t = (size_t)(brow + r_loc);
                float lo = acc[mi][ni][i] + bl;
                const float* P = &Plds[r_loc * 24];
                const float* xt = x + t * 8192 + cg;
                float xm0 = xt[0], xm1 = xt[2048], xm2 = xt[4096], xm3 = xt[6144];
                float* ot = out + t * 8192 + cg;
#pragma unroll
                for (int n = 0; n < 4; ++n) {
                    float v = P[4 + n] * lo;
                    v += P[8 + n * 4 + 0] * xm0;
                    v += P[8 + n * 4 + 1] * xm1;
                    v += P[8 + n * 4 + 2] * xm2;
                    v += P[8 + n * 4 + 3] * xm3;
                    ot[(size_t)n * 2048] = v;
                }
            }
        }
    }
}

extern "C" void kernel_launch(void* const* d_in, const int* in_sizes, int n_in,
                              void* d_out, int out_size, void* d_ws, size_t ws_size,
                              hipStream_t stream) {
    const float* x       = (const float*)d_in[0];
    const float* W_all   = (const float*)d_in[1];
    const float* b_all   = (const float*)d_in[2];
    const float* a_pre   = (const float*)d_in[3];
    const float* a_post  = (const float*)d_in[4];
    const float* a_res   = (const float*)d_in[5];
    const float* perm    = (const float*)d_in[6];
    const float* W_layer = (const float*)d_in[7];
    const float* b_layer = (const float*)d_in[8];
    float* out = (float*)d_out;

    char* ws = (char*)d_ws;
    ushort* wall_b   = (ushort*)(ws);                                        // 512 KB
    ushort* wlayer_b = (ushort*)(ws + (512u << 10));                         // 8 MB
    float*  params   = (float*)(ws + (512u << 10) + (8u << 20));             // 768 KB
    ushort* li       = (ushort*)(ws + (512u << 10) + (8u << 20) + (768u << 10)); // 32 MB

    k_cvt<<<dim3(256), dim3(256), 0, stream>>>(W_all, wall_b, 65536);
    k_cvt<<<dim3(4096), dim3(256), 0, stream>>>(W_layer, wlayer_b, 1048576);
    k_stats<<<dim3(256), dim3(512), 0, stream>>>(x, wall_b, b_all, a_pre, a_post, a_res,
                                                 perm, params, li);
    k_gemm_out<<<dim3(64, 16), dim3(256), 0, stream>>>(li, wlayer_b, b_layer, params, x, out);
}

// Round 2
// 383.440 us; speedup vs baseline: 1.4317x; 1.4317x over previous
//
#include <hip/hip_runtime.h>

typedef __attribute__((ext_vector_type(8))) short bf16x8;
typedef __attribute__((ext_vector_type(4))) float f32x4;

#if defined(__has_builtin)
#if __has_builtin(__builtin_amdgcn_global_load_lds)
#define HAVE_GLL 1
#endif
#endif

__device__ __forceinline__ ushort f2bf(float f) {
    unsigned u = __float_as_uint(f);
    u += 0x7fffu + ((u >> 16) & 1u);   // round-to-nearest-even
    return (ushort)(u >> 16);
}

// global->LDS 16B stage. GLL path: lbase is wave-uniform, HW adds lane*16.
__device__ __forceinline__ void stage16(const ushort* __restrict__ g, ushort* lbase, int lane) {
#ifdef HAVE_GLL
    __builtin_amdgcn_global_load_lds((const __attribute__((address_space(1))) void*)g,
                                     (__attribute__((address_space(3))) void*)lbase,
                                     16, 0, 0);
#else
    *(float4*)(lbase + lane * 8) = *(const float4*)g;
#endif
}

// ---------------- K0: f32 -> bf16 weight conversion ----------------
__global__ void k_cvt(const float* __restrict__ src, ushort* __restrict__ dst, int n4) {
    int i = blockIdx.x * blockDim.x + threadIdx.x;
    if (i >= n4) return;
    float4 v = ((const float4*)src)[i];
    ushort4 o;
    o.x = f2bf(v.x); o.y = f2bf(v.y); o.z = f2bf(v.z); o.w = f2bf(v.w);
    ((ushort4*)dst)[i] = o;
}

// ---------------- K1: per-row stats + params + layer_input ----------------
// block = 512 threads (8 waves), 32 rows/block, grid = 256.
__global__ __launch_bounds__(512) void k_stats(
    const float* __restrict__ x,        // [8192][8192]
    const ushort* __restrict__ wallb,   // [32][8192] bf16
    const float* __restrict__ b_all,    // [32]
    const float* __restrict__ a_pre, const float* __restrict__ a_post,
    const float* __restrict__ a_res,
    const float* __restrict__ perm,     // [24][16]
    float* __restrict__ params,         // [8192][24]: h_pre[4] h_post[4] Hm[16]
    ushort* __restrict__ li)            // [8192][2048] bf16
{
    __shared__ ushort Alds[2][32 * 64];
    __shared__ ushort Blds[2][32 * 64];
    __shared__ float dots_s[2][32][33];
    __shared__ float ssq_l[512];
    __shared__ float hpre_l[32][4];

    const int tid = threadIdx.x;
    const int lane = tid & 63;
    const int wv = tid >> 6;
    const int brow = blockIdx.x * 32;

    const int kh = tid >> 8;       // staging K-half
    const int h = tid & 255;
    const int sr = h >> 3;         // row 0..31 (also W_all row j)
    const int sk = (h & 7) * 8;

    const float* __restrict__ xrow = x + (size_t)(brow + sr) * 8192 + kh * 4096 + sk;
    const ushort* __restrict__ wrow = wallb + (size_t)sr * 8192 + kh * 4096 + sk;

    float4 ra0 = *(const float4*)(xrow);
    float4 ra1 = *(const float4*)(xrow + 4);
    float4 rb = *(const float4*)(wrow);

    const int kh_w = wv >> 2, mt = wv & 1, jt = (wv >> 1) & 1;
    const ushort* Abase = &Alds[kh_w][(mt * 16 + (lane & 15)) * 64 + ((lane >> 4) * 8)];
    const ushort* Bbase = &Blds[kh_w][(jt * 16 + (lane & 15)) * 64 + ((lane >> 4) * 8)];

    f32x4 acc = {0.f, 0.f, 0.f, 0.f};
    float ssq = 0.f;

    for (int step = 0; step < 64; ++step) {
        __syncthreads();
        float va[8] = {ra0.x, ra0.y, ra0.z, ra0.w, ra1.x, ra1.y, ra1.z, ra1.w};
        union { ushort u[8]; float4 f; } pk;
#pragma unroll
        for (int j = 0; j < 8; ++j) { float v = va[j]; ssq += v * v; pk.u[j] = f2bf(v); }
        *(float4*)&Alds[kh][sr * 64 + sk] = pk.f;
        *(float4*)&Blds[kh][sr * 64 + sk] = rb;
        __syncthreads();
        if (step + 1 < 64) {   // prefetch next tile while MFMA runs
            const float* xp = xrow + (step + 1) * 64;
            ra0 = *(const float4*)(xp);
            ra1 = *(const float4*)(xp + 4);
            rb = *(const float4*)(wrow + (step + 1) * 64);
        }
        bf16x8 a0 = *(const bf16x8*)(Abase);
        bf16x8 a1 = *(const bf16x8*)(Abase + 32);
        bf16x8 b0 = *(const bf16x8*)(Bbase);
        bf16x8 b1 = *(const bf16x8*)(Bbase + 32);
        acc = __builtin_amdgcn_mfma_f32_16x16x32_bf16(a0, b0, acc, 0, 0, 0);
        acc = __builtin_amdgcn_mfma_f32_16x16x32_bf16(a1, b1, acc, 0, 0, 0);
    }

#pragma unroll
    for (int i = 0; i < 4; ++i)
        dots_s[kh_w][mt * 16 + (lane >> 4) * 4 + i][jt * 16 + (lane & 15)] = acc[i];
    ssq_l[tid] = ssq;
    __syncthreads();

    if (tid < 32) {   // one thread per row: scalar epilogue
        float s = 0.f;
#pragma unroll
        for (int q = 0; q < 8; ++q) s += ssq_l[tid * 8 + q] + ssq_l[256 + tid * 8 + q];
        float inv_rms = rsqrtf(s * (1.0f / 8192.0f) + 1.1920929e-7f);
        float pj[32];
#pragma unroll
        for (int j = 0; j < 32; ++j)
            pj[j] = (dots_s[0][tid][j] + dots_s[1][tid][j]) * inv_rms;
        float ap = a_pre[0], apo = a_post[0], ar = a_res[0];
        float hpre[4], hpost[4];
#pragma unroll
        for (int n = 0; n < 4; ++n) {
            hpre[n] = 1.0f / (1.0f + expf(-(ap * pj[n] + b_all[n])));
            hpost[n] = 2.0f / (1.0f + expf(-(apo * pj[4 + n] + b_all[4 + n])));
        }
        float z[24]; float mx = -1e30f;
#pragma unroll
        for (int p = 0; p < 24; ++p) { z[p] = ar * pj[8 + p] + b_all[8 + p]; mx = fmaxf(mx, z[p]); }
        float se = 0.f;
#pragma unroll
        for (int p = 0; p < 24; ++p) { z[p] = expf(z[p] - mx); se += z[p]; }
        float isum = 1.0f / se;
        float Hr[16];
#pragma unroll
        for (int e = 0; e < 16; ++e) Hr[e] = 0.f;
#pragma unroll
        for (int p = 0; p < 24; ++p) {
            float a = z[p] * isum;
#pragma unroll
            for (int e = 0; e < 16; ++e) Hr[e] += a * perm[p * 16 + e];
        }
        float* P = params + (size_t)(brow + tid) * 24;
#pragma unroll
        for (int n = 0; n < 4; ++n) { P[n] = hpre[n]; P[4 + n] = hpost[n]; hpre_l[tid][n] = hpre[n]; }
#pragma unroll
        for (int n = 0; n < 4; ++n)
#pragma unroll
            for (int m = 0; m < 4; ++m)
                P[8 + n * 4 + m] = Hr[n * 4 + m] - hpost[n] * hpre[m];
    }
    __syncthreads();

    // layer_input phase: rows hot in L2 from the k-loop
    const int c = tid * 4;
#pragma unroll 4
    for (int r = 0; r < 32; ++r) {
        float h0 = hpre_l[r][0], h1 = hpre_l[r][1], h2 = hpre_l[r][2], h3 = hpre_l[r][3];
        const float* xr = x + (size_t)(brow + r) * 8192 + c;
        float4 a0 = *(const float4*)(xr);
        float4 a1 = *(const float4*)(xr + 2048);
        float4 a2 = *(const float4*)(xr + 4096);
        float4 a3 = *(const float4*)(xr + 6144);
        ushort4 ob;
        ob.x = f2bf(h0 * a0.x + h1 * a1.x + h2 * a2.x + h3 * a3.x);
        ob.y = f2bf(h0 * a0.y + h1 * a1.y + h2 * a2.y + h3 * a3.y);
        ob.z = f2bf(h0 * a0.z + h1 * a1.z + h2 * a2.z + h3 * a3.z);
        ob.w = f2bf(h0 * a0.w + h1 * a1.w + h2 * a2.w + h3 * a3.w);
        *(ushort4*)(li + (size_t)(brow + r) * 2048 + c) = ob;
    }
}

// ---------------- K3: GEMM (li @ W_layer^T) + fused final combine ----------------
// 128x128 tile, BK=64, 4 waves. T2 XOR-swizzled LDS (pre-swizzled global src,
// rule 21). MFMA operands SWAPPED (bg, af) so lane's 4 acc elems are 4
// CONSECUTIVE c values -> float4 epilogue.
__global__ __launch_bounds__(256) void k_gemm_out(
    const ushort* __restrict__ liA,    // [8192][2048] bf16
    const ushort* __restrict__ WB,     // [2048][2048] bf16 (c,k) = B^T layout
    const float* __restrict__ b_layer, // [2048]
    const float* __restrict__ params,  // [8192][24]
    const float* __restrict__ x,       // [8192][8192]
    float* __restrict__ out)           // [8192][4][2048]
{
    __shared__ ushort Alds[128 * 64];
    __shared__ ushort Blds[128 * 64];
    __shared__ float Plds[128 * 25];   // stride 25: odd -> conflict-free
    __shared__ float bl_s[128];

    const int tid = threadIdx.x;
    const int ln = tid & 63;
    const int wv = tid >> 6;
    const int brow = blockIdx.x * 128;
    const int bcol = blockIdx.y * 128;

    for (int i = tid; i < 128 * 24; i += 256) {
        int r = i / 24, j = i - r * 24;
        Plds[r * 25 + j] = params[(size_t)brow * 24 + i];
    }
    if (tid < 128) bl_s[tid] = b_layer[bcol + tid];

    f32x4 acc[4][4] = {};

    const int srow = ln >> 3;                         // staging row within 8-row group
    const int scol = (((ln & 7) ^ (ln >> 3)) * 8);    // pre-swizzled source col (ushort)
    const int wm = wv >> 1, wn = wv & 1;
    const int fr = ln & 15, fq = ln >> 4;
    const int swz = (fr & 7) << 3;                    // read-side XOR (ushort units)

    for (int k0 = 0; k0 < 2048; k0 += 64) {
        __syncthreads();
#pragma unroll
        for (int q = 0; q < 4; ++q) {
            int row = wv * 32 + q * 8 + srow;
            stage16(liA + (size_t)(brow + row) * 2048 + k0 + scol, &Alds[wv * 2048 + q * 512], ln);
            stage16(WB + (size_t)(bcol + row) * 2048 + k0 + scol, &Blds[wv * 2048 + q * 512], ln);
        }
        __syncthreads();
#pragma unroll
        for (int kk = 0; kk < 64; kk += 32) {
            bf16x8 af[4], bg[4];
#pragma unroll
            for (int mi = 0; mi < 4; ++mi)
                af[mi] = *(const bf16x8*)&Alds[(wm * 64 + mi * 16 + fr) * 64 + ((kk + fq * 8) ^ swz)];
#pragma unroll
            for (int ni = 0; ni < 4; ++ni)
                bg[ni] = *(const bf16x8*)&Blds[(wn * 64 + ni * 16 + fr) * 64 + ((kk + fq * 8) ^ swz)];
#pragma unroll
            for (int mi = 0; mi < 4; ++mi)
#pragma unroll
                for (int ni = 0; ni < 4; ++ni)
                    acc[mi][ni] = __builtin_amdgcn_mfma_f32_16x16x32_bf16(bg[ni], af[mi], acc[mi][ni], 0, 0, 0);
        }
    }

    // Epilogue. Swapped operands: D[row=c][col=t]; lane holds t = ...+fr and
    // c = ...+fq*4+i (4 consecutive) -> float4 loads/stores.
    // out[t,n,c] = sum_m Hm[n,m]*x[t,m,c] + h_post[n]*(acc + b_layer[c])
#pragma unroll
    for (int mi = 0; mi < 4; ++mi) {
        const int t_loc = wm * 64 + mi * 16 + fr;
        const size_t t = (size_t)(brow + t_loc);
        const float* P = &Plds[t_loc * 25];
        float hp0 = P[4], hp1 = P[5], hp2 = P[6], hp3 = P[7];
        float Hm[16];
#pragma unroll
        for (int e = 0; e < 16; ++e) Hm[e] = P[8 + e];
        const float* xt = x + t * 8192;
        float* ot = out + t * 8192;
#pragma unroll
        for (int ni = 0; ni < 4; ++ni) {
            const int c_loc = wn * 64 + ni * 16 + fq * 4;
            const int cg = bcol + c_loc;
            float4 bl = *(const float4*)&bl_s[c_loc];
            float4 x0 = *(const float4*)(xt + cg);
            float4 x1 = *(const float4*)(xt + 2048 + cg);
            float4 x2 = *(const float4*)(xt + 4096 + cg);
            float4 x3 = *(const float4*)(xt + 6144 + cg);
            float4 lo;
            lo.x = acc[mi][ni][0] + bl.x;
            lo.y = acc[mi][ni][1] + bl.y;
            lo.z = acc[mi][ni][2] + bl.z;
            lo.w = acc[mi][ni][3] + bl.w;
            float hp[4] = {hp0, hp1, hp2, hp3};
#pragma unroll
            for (int n = 0; n < 4; ++n) {
                float4 v;
                v.x = hp[n] * lo.x + Hm[n*4+0] * x0.x + Hm[n*4+1] * x1.x + Hm[n*4+2] * x2.x + Hm[n*4+3] * x3.x;
                v.y = hp[n] * lo.y + Hm[n*4+0] * x0.y + Hm[n*4+1] * x1.y + Hm[n*4+2] * x2.y + Hm[n*4+3] * x3.y;
                v.z = hp[n] * lo.z + Hm[n*4+0] * x0.z + Hm[n*4+1] * x1.z + Hm[n*4+2] * x2.z + Hm[n*4+3] * x3.z;
                v.w = hp[n] * lo.w + Hm[n*4+0] * x0.w + Hm[n*4+1] * x1.w + Hm[n*4+2] * x2.w + Hm[n*4+3] * x3.w;
                *(float4*)(ot + (size_t)n * 2048 + cg) = v;
            }
        }
    }
}

extern "C" void kernel_launch(void* const* d_in, const int* in_sizes, int n_in,
                              void* d_out, int out_size, void* d_ws, size_t ws_size,
                              hipStream_t stream) {
    const float* x       = (const float*)d_in[0];
    const float* W_all   = (const float*)d_in[1];
    const float* b_all   = (const float*)d_in[2];
    const float* a_pre   = (const float*)d_in[3];
    const float* a_post  = (const float*)d_in[4];
    const float* a_res   = (const float*)d_in[5];
    const float* perm    = (const float*)d_in[6];
    const float* W_layer = (const float*)d_in[7];
    const float* b_layer = (const float*)d_in[8];
    float* out = (float*)d_out;

    char* ws = (char*)d_ws;
    ushort* wall_b   = (ushort*)(ws);                                        // 512 KB
    ushort* wlayer_b = (ushort*)(ws + (512u << 10));                         // 8 MB
    float*  params   = (float*)(ws + (512u << 10) + (8u << 20));             // 768 KB
    ushort* li       = (ushort*)(ws + (512u << 10) + (8u << 20) + (768u << 10)); // 32 MB

    k_cvt<<<dim3(256), dim3(256), 0, stream>>>(W_all, wall_b, 65536);
    k_cvt<<<dim3(4096), dim3(256), 0, stream>>>(W_layer, wlayer_b, 1048576);
    k_stats<<<dim3(256), dim3(512), 0, stream>>>(x, wall_b, b_all, a_pre, a_post, a_res,
                                                 perm, params, li);
    k_gemm_out<<<dim3(64, 16), dim3(256), 0, stream>>>(li, wlayer_b, b_layer, params, x, out);
}

// Round 3
// 370.754 us; speedup vs baseline: 1.4807x; 1.0342x over previous
//
#include <hip/hip_runtime.h>

typedef __attribute__((ext_vector_type(8))) short bf16x8;
typedef __attribute__((ext_vector_type(4))) float f32x4;

#if defined(__has_builtin)
#if __has_builtin(__builtin_amdgcn_global_load_lds)
#define HAVE_GLL 1
#endif
#endif

__device__ __forceinline__ ushort f2bf(float f) {
    unsigned u = __float_as_uint(f);
    u += 0x7fffu + ((u >> 16) & 1u);   // round-to-nearest-even
    return (ushort)(u >> 16);
}

// global->LDS 16B stage. GLL path: lbase is wave-uniform, HW adds lane*16.
__device__ __forceinline__ void stage16(const ushort* __restrict__ g, ushort* lbase, int lane) {
#ifdef HAVE_GLL
    __builtin_amdgcn_global_load_lds((const __attribute__((address_space(1))) void*)g,
                                     (__attribute__((address_space(3))) void*)lbase,
                                     16, 0, 0);
#else
    *(float4*)(lbase + lane * 8) = *(const float4*)g;
#endif
}

// ---------------- K0: f32 -> bf16 weight conversion ----------------
__global__ void k_cvt(const float* __restrict__ src, ushort* __restrict__ dst, int n4) {
    int i = blockIdx.x * blockDim.x + threadIdx.x;
    if (i >= n4) return;
    float4 v = ((const float4*)src)[i];
    ushort4 o;
    o.x = f2bf(v.x); o.y = f2bf(v.y); o.z = f2bf(v.z); o.w = f2bf(v.w);
    ((ushort4*)dst)[i] = o;
}

// ---------------- K1: per-row stats + params + layer_input ----------------
// 512 blocks x 512 threads (8 waves). 16 rows/block; wave wq owns k-eighth.
// MFMA A/B fragments built DIRECTLY in registers (no LDS staging, no
// barriers in the k-loop). dot(x_norm,w) = inv_rms*dot(x,w).
__global__ __launch_bounds__(512) void k_stats(
    const float* __restrict__ x,        // [8192][8192]
    const ushort* __restrict__ wallb,   // [32][8192] bf16
    const float* __restrict__ b_all,    // [32]
    const float* __restrict__ a_pre, const float* __restrict__ a_post,
    const float* __restrict__ a_res,
    const float* __restrict__ perm,     // [24][16]
    float* __restrict__ params,         // [8192][24]: h_pre[4] h_post[4] Hm[16]
    ushort* __restrict__ li)            // [8192][2048] bf16
{
    __shared__ float dots[8][16][33];
    __shared__ float ssq_s[8][16];
    __shared__ float hpre_l[16][4];

    const int tid = threadIdx.x;
    const int lane = tid & 63;
    const int wq = tid >> 6;            // k-eighth 0..7
    const int r = lane & 15;            // x-row / W-row within group
    const int kg = lane >> 4;           // k-subgroup 0..3
    const int brow = blockIdx.x * 16;

    const float* xp = x + (size_t)(brow + r) * 8192 + wq * 1024 + kg * 8;
    const ushort* wp0 = wallb + (size_t)r * 8192 + wq * 1024 + kg * 8;
    const ushort* wp1 = wp0 + 16 * 8192;

    f32x4 acc0 = {}, acc1 = {};
    float ssq = 0.f;

#pragma unroll 4
    for (int s = 0; s < 32; ++s) {
        const int off = s * 32;
        float4 a0 = *(const float4*)(xp + off);
        float4 a1 = *(const float4*)(xp + off + 4);
        float va[8] = {a0.x, a0.y, a0.z, a0.w, a1.x, a1.y, a1.z, a1.w};
        union { ushort u[8]; bf16x8 v; } av;
#pragma unroll
        for (int j = 0; j < 8; ++j) { ssq += va[j] * va[j]; av.u[j] = f2bf(va[j]); }
        bf16x8 b0 = *(const bf16x8*)(wp0 + off);
        bf16x8 b1 = *(const bf16x8*)(wp1 + off);
        acc0 = __builtin_amdgcn_mfma_f32_16x16x32_bf16(av.v, b0, acc0, 0, 0, 0);
        acc1 = __builtin_amdgcn_mfma_f32_16x16x32_bf16(av.v, b1, acc1, 0, 0, 0);
    }

    // ssq: reduce over the 4 kg-groups holding the same row
    ssq += __shfl_xor(ssq, 16);
    ssq += __shfl_xor(ssq, 32);
    if (lane < 16) ssq_s[wq][r] = ssq;
    // D layout: row=(lane>>4)*4+i (x-row), col=lane&15 (j)
#pragma unroll
    for (int i = 0; i < 4; ++i) {
        dots[wq][kg * 4 + i][r] = acc0[i];
        dots[wq][kg * 4 + i][16 + r] = acc1[i];
    }
    __syncthreads();

    if (tid < 16) {   // one thread per row: scalar epilogue
        float s = 0.f;
#pragma unroll
        for (int q = 0; q < 8; ++q) s += ssq_s[q][tid];
        float inv_rms = rsqrtf(s * (1.0f / 8192.0f) + 1.1920929e-7f);
        float pj[32];
#pragma unroll
        for (int j = 0; j < 32; ++j) {
            float d = 0.f;
#pragma unroll
            for (int q = 0; q < 8; ++q) d += dots[q][tid][j];
            pj[j] = d * inv_rms;
        }
        float ap = a_pre[0], apo = a_post[0], ar = a_res[0];
        float hpre[4], hpost[4];
#pragma unroll
        for (int n = 0; n < 4; ++n) {
            hpre[n] = 1.0f / (1.0f + expf(-(ap * pj[n] + b_all[n])));
            hpost[n] = 2.0f / (1.0f + expf(-(apo * pj[4 + n] + b_all[4 + n])));
        }
        float z[24]; float mx = -1e30f;
#pragma unroll
        for (int p = 0; p < 24; ++p) { z[p] = ar * pj[8 + p] + b_all[8 + p]; mx = fmaxf(mx, z[p]); }
        float se = 0.f;
#pragma unroll
        for (int p = 0; p < 24; ++p) { z[p] = expf(z[p] - mx); se += z[p]; }
        float isum = 1.0f / se;
        float Hr[16];
#pragma unroll
        for (int e = 0; e < 16; ++e) Hr[e] = 0.f;
#pragma unroll
        for (int p = 0; p < 24; ++p) {
            float a = z[p] * isum;
#pragma unroll
            for (int e = 0; e < 16; ++e) Hr[e] += a * perm[p * 16 + e];
        }
        float* P = params + (size_t)(brow + tid) * 24;
#pragma unroll
        for (int n = 0; n < 4; ++n) { P[n] = hpre[n]; P[4 + n] = hpost[n]; hpre_l[tid][n] = hpre[n]; }
#pragma unroll
        for (int n = 0; n < 4; ++n)
#pragma unroll
            for (int m = 0; m < 4; ++m)
                P[8 + n * 4 + m] = Hr[n * 4 + m] - hpost[n] * hpre[m];
    }
    __syncthreads();

    // layer_input phase: block's x rows just streamed -> L2/L3-warm
    const int c = tid * 4;
#pragma unroll 2
    for (int rr = 0; rr < 16; ++rr) {
        float h0 = hpre_l[rr][0], h1 = hpre_l[rr][1], h2 = hpre_l[rr][2], h3 = hpre_l[rr][3];
        const float* xr = x + (size_t)(brow + rr) * 8192 + c;
        float4 a0 = *(const float4*)(xr);
        float4 a1 = *(const float4*)(xr + 2048);
        float4 a2 = *(const float4*)(xr + 4096);
        float4 a3 = *(const float4*)(xr + 6144);
        ushort4 ob;
        ob.x = f2bf(h0 * a0.x + h1 * a1.x + h2 * a2.x + h3 * a3.x);
        ob.y = f2bf(h0 * a0.y + h1 * a1.y + h2 * a2.y + h3 * a3.y);
        ob.z = f2bf(h0 * a0.z + h1 * a1.z + h2 * a2.z + h3 * a3.z);
        ob.w = f2bf(h0 * a0.w + h1 * a1.w + h2 * a2.w + h3 * a3.w);
        *(ushort4*)(li + (size_t)(brow + rr) * 2048 + c) = ob;
    }
}

// ---------------- K3: GEMM (li @ W_layer^T) + fused final combine ----------------
// 128x128 tile, BK=64, 4 waves. 2-phase double-buffer (T3 minimum): issue
// STAGE(next) before compute(cur), ONE barrier per K-tile. T2 XOR-swizzled
// LDS (pre-swizzled source, rule 21). Swapped MFMA operands -> float4
// epilogue. XCD-aware bijective block swizzle (T1, nwg=1024 %8==0).
__global__ __launch_bounds__(256) void k_gemm_out(
    const ushort* __restrict__ liA,    // [8192][2048] bf16
    const ushort* __restrict__ WB,     // [2048][2048] bf16 (c,k) = B^T layout
    const float* __restrict__ b_layer, // [2048]
    const float* __restrict__ params,  // [8192][24]
    const float* __restrict__ x,       // [8192][8192]
    float* __restrict__ out)           // [8192][4][2048]
{
    __shared__ ushort Alds[2][128 * 64];
    __shared__ ushort Blds[2][128 * 64];
    __shared__ float Plds[128 * 25];
    __shared__ float bl_s[128];

    const int tid = threadIdx.x;
    const int ln = tid & 63;
    const int wv = tid >> 6;

    // XCD swizzle: each XCD gets 2 consecutive col-panels x all row-tiles
    const int orig = blockIdx.y * 64 + blockIdx.x;
    const int newid = (orig & 7) * 128 + (orig >> 3);
    const int brow = (newid & 63) * 128;
    const int bcol = (newid >> 6) * 128;

    for (int i = tid; i < 128 * 24; i += 256) {
        int r = i / 24, j = i - r * 24;
        Plds[r * 25 + j] = params[(size_t)(brow + r) * 24 + j];
    }
    if (tid < 128) bl_s[tid] = b_layer[bcol + tid];

    f32x4 acc[4][4] = {};

    const int srow = ln >> 3;                       // staging row within 8-row group
    const int scol = ((ln & 7) ^ srow) * 8;         // pre-swizzled source col
    const int wm = wv >> 1, wn = wv & 1;
    const int fr = ln & 15, fq = ln >> 4;
    const int swz = (fr & 7) << 3;                  // read-side XOR (ushort units)

    auto do_stage = [&](int buf, int k0) {
#pragma unroll
        for (int q = 0; q < 4; ++q) {
            int row = wv * 32 + q * 8 + srow;
            stage16(liA + (size_t)(brow + row) * 2048 + k0 + scol, &Alds[buf][wv * 2048 + q * 512], ln);
            stage16(WB + (size_t)(bcol + row) * 2048 + k0 + scol, &Blds[buf][wv * 2048 + q * 512], ln);
        }
    };

    do_stage(0, 0);
    __syncthreads();             // drains prologue stage (vmcnt0 + barrier)

    int cur = 0;
    for (int k0 = 0; k0 < 2048; k0 += 64) {
        if (k0 + 64 < 2048) do_stage(cur ^ 1, k0 + 64);   // prefetch flies under MFMA
#pragma unroll
        for (int kk = 0; kk < 64; kk += 32) {
            bf16x8 af[4], bg[4];
#pragma unroll
            for (int mi = 0; mi < 4; ++mi)
                af[mi] = *(const bf16x8*)&Alds[cur][(wm * 64 + mi * 16 + fr) * 64 + ((kk + fq * 8) ^ swz)];
#pragma unroll
            for (int ni = 0; ni < 4; ++ni)
                bg[ni] = *(const bf16x8*)&Blds[cur][(wn * 64 + ni * 16 + fr) * 64 + ((kk + fq * 8) ^ swz)];
#pragma unroll
            for (int mi = 0; mi < 4; ++mi)
#pragma unroll
                for (int ni = 0; ni < 4; ++ni)
                    acc[mi][ni] = __builtin_amdgcn_mfma_f32_16x16x32_bf16(bg[ni], af[mi], acc[mi][ni], 0, 0, 0);
        }
        __syncthreads();         // one barrier per K-tile: drains prefetch + guards reuse
        cur ^= 1;
    }

    // Epilogue. Swapped operands: lane holds t=...+fr, c=...+fq*4+i -> float4 I/O.
    // out[t,n,c] = sum_m Hm[n,m]*x[t,m,c] + h_post[n]*(acc + b_layer[c])
#pragma unroll
    for (int mi = 0; mi < 4; ++mi) {
        const int t_loc = wm * 64 + mi * 16 + fr;
        const size_t t = (size_t)(brow + t_loc);
        const float* P = &Plds[t_loc * 25];
        float hp0 = P[4], hp1 = P[5], hp2 = P[6], hp3 = P[7];
        float Hm[16];
#pragma unroll
        for (int e = 0; e < 16; ++e) Hm[e] = P[8 + e];
        const float* xt = x + t * 8192;
        float* ot = out + t * 8192;
#pragma unroll
        for (int ni = 0; ni < 4; ++ni) {
            const int c_loc = wn * 64 + ni * 16 + fq * 4;
            const int cg = bcol + c_loc;
            float4 bl = *(const float4*)&bl_s[c_loc];
            float4 x0 = *(const float4*)(xt + cg);
            float4 x1 = *(const float4*)(xt + 2048 + cg);
            float4 x2 = *(const float4*)(xt + 4096 + cg);
            float4 x3 = *(const float4*)(xt + 6144 + cg);
            float4 lo;
            lo.x = acc[mi][ni][0] + bl.x;
            lo.y = acc[mi][ni][1] + bl.y;
            lo.z = acc[mi][ni][2] + bl.z;
            lo.w = acc[mi][ni][3] + bl.w;
            float hp[4] = {hp0, hp1, hp2, hp3};
#pragma unroll
            for (int n = 0; n < 4; ++n) {
                float4 v;
                v.x = hp[n] * lo.x + Hm[n*4+0] * x0.x + Hm[n*4+1] * x1.x + Hm[n*4+2] * x2.x + Hm[n*4+3] * x3.x;
                v.y = hp[n] * lo.y + Hm[n*4+0] * x0.y + Hm[n*4+1] * x1.y + Hm[n*4+2] * x2.y + Hm[n*4+3] * x3.y;
                v.z = hp[n] * lo.z + Hm[n*4+0] * x0.z + Hm[n*4+1] * x1.z + Hm[n*4+2] * x2.z + Hm[n*4+3] * x3.z;
                v.w = hp[n] * lo.w + Hm[n*4+0] * x0.w + Hm[n*4+1] * x1.w + Hm[n*4+2] * x2.w + Hm[n*4+3] * x3.w;
                *(float4*)(ot + (size_t)n * 2048 + cg) = v;
            }
        }
    }
}

extern "C" void kernel_launch(void* const* d_in, const int* in_sizes, int n_in,
                              void* d_out, int out_size, void* d_ws, size_t ws_size,
                              hipStream_t stream) {
    const float* x       = (const float*)d_in[0];
    const float* W_all   = (const float*)d_in[1];
    const float* b_all   = (const float*)d_in[2];
    const float* a_pre   = (const float*)d_in[3];
    const float* a_post  = (const float*)d_in[4];
    const float* a_res   = (const float*)d_in[5];
    const float* perm    = (const float*)d_in[6];
    const float* W_layer = (const float*)d_in[7];
    const float* b_layer = (const float*)d_in[8];
    float* out = (float*)d_out;

    char* ws = (char*)d_ws;
    ushort* wall_b   = (ushort*)(ws);                                        // 512 KB
    ushort* wlayer_b = (ushort*)(ws + (512u << 10));                         // 8 MB
    float*  params   = (float*)(ws + (512u << 10) + (8u << 20));             // 768 KB
    ushort* li       = (ushort*)(ws + (512u << 10) + (8u << 20) + (768u << 10)); // 32 MB

    k_cvt<<<dim3(256), dim3(256), 0, stream>>>(W_all, wall_b, 65536);
    k_cvt<<<dim3(4096), dim3(256), 0, stream>>>(W_layer, wlayer_b, 1048576);
    k_stats<<<dim3(512), dim3(512), 0, stream>>>(x, wall_b, b_all, a_pre, a_post, a_res,
                                                 perm, params, li);
    k_gemm_out<<<dim3(64, 16), dim3(256), 0, stream>>>(li, wlayer_b, b_layer, params, x, out);
}

// Round 6
// 363.623 us; speedup vs baseline: 1.5097x; 1.0196x over previous
//
#include <hip/hip_runtime.h>

typedef __attribute__((ext_vector_type(8))) short bf16x8;
typedef __attribute__((ext_vector_type(4))) float f32x4;

#if defined(__has_builtin)
#if __has_builtin(__builtin_amdgcn_global_load_lds)
#define HAVE_GLL 1
#endif
#endif

__device__ __forceinline__ ushort f2bf(float f) {
    unsigned u = __float_as_uint(f);
    u += 0x7fffu + ((u >> 16) & 1u);   // round-to-nearest-even
    return (ushort)(u >> 16);
}

// global->LDS 16B stage. GLL path: lbase is wave-uniform, HW adds lane*16.
__device__ __forceinline__ void stage16(const ushort* __restrict__ g, ushort* lbase, int lane) {
#ifdef HAVE_GLL
    __builtin_amdgcn_global_load_lds((const __attribute__((address_space(1))) void*)g,
                                     (__attribute__((address_space(3))) void*)lbase,
                                     16, 0, 0);
#else
    *(float4*)(lbase + lane * 8) = *(const float4*)g;
#endif
}

// ---------------- K0: f32 -> bf16 weight conversion ----------------
__global__ void k_cvt(const float* __restrict__ src, ushort* __restrict__ dst, int n4) {
    int i = blockIdx.x * blockDim.x + threadIdx.x;
    if (i >= n4) return;
    float4 v = ((const float4*)src)[i];
    ushort4 o;
    o.x = f2bf(v.x); o.y = f2bf(v.y); o.z = f2bf(v.z); o.w = f2bf(v.w);
    ((ushort4*)dst)[i] = o;
}

// ---------------- K1: per-row stats + params + layer_input ----------------
// 512 blocks x 512 threads (8 waves). 16 rows/block; wave wq owns k-eighth.
// MFMA A/B fragments built DIRECTLY in registers (no LDS staging, no
// barriers in the k-loop). dot(x_norm,w) = inv_rms*dot(x,w).
__global__ __launch_bounds__(512) void k_stats(
    const float* __restrict__ x,        // [8192][8192]
    const ushort* __restrict__ wallb,   // [32][8192] bf16
    const float* __restrict__ b_all,    // [32]
    const float* __restrict__ a_pre, const float* __restrict__ a_post,
    const float* __restrict__ a_res,
    const float* __restrict__ perm,     // [24][16]
    float* __restrict__ params,         // [8192][24]: h_pre[4] h_post[4] Hm[16]
    ushort* __restrict__ li)            // [8192][2048] bf16
{
    __shared__ float dots[8][16][33];
    __shared__ float ssq_s[8][16];
    __shared__ float hpre_l[16][4];

    const int tid = threadIdx.x;
    const int lane = tid & 63;
    const int wq = tid >> 6;            // k-eighth 0..7
    const int r = lane & 15;            // x-row / W-row within group
    const int kg = lane >> 4;           // k-subgroup 0..3
    const int brow = blockIdx.x * 16;

    const float* xp = x + (size_t)(brow + r) * 8192 + wq * 1024 + kg * 8;
    const ushort* wp0 = wallb + (size_t)r * 8192 + wq * 1024 + kg * 8;
    const ushort* wp1 = wp0 + 16 * 8192;

    f32x4 acc0 = {}, acc1 = {};
    float ssq = 0.f;

#pragma unroll 4
    for (int s = 0; s < 32; ++s) {
        const int off = s * 32;
        float4 a0 = *(const float4*)(xp + off);
        float4 a1 = *(const float4*)(xp + off + 4);
        float va[8] = {a0.x, a0.y, a0.z, a0.w, a1.x, a1.y, a1.z, a1.w};
        union { ushort u[8]; bf16x8 v; } av;
#pragma unroll
        for (int j = 0; j < 8; ++j) { ssq += va[j] * va[j]; av.u[j] = f2bf(va[j]); }
        bf16x8 b0 = *(const bf16x8*)(wp0 + off);
        bf16x8 b1 = *(const bf16x8*)(wp1 + off);
        acc0 = __builtin_amdgcn_mfma_f32_16x16x32_bf16(av.v, b0, acc0, 0, 0, 0);
        acc1 = __builtin_amdgcn_mfma_f32_16x16x32_bf16(av.v, b1, acc1, 0, 0, 0);
    }

    // ssq: reduce over the 4 kg-groups holding the same row
    ssq += __shfl_xor(ssq, 16);
    ssq += __shfl_xor(ssq, 32);
    if (lane < 16) ssq_s[wq][r] = ssq;
    // D layout: row=(lane>>4)*4+i (x-row), col=lane&15 (j)
#pragma unroll
    for (int i = 0; i < 4; ++i) {
        dots[wq][kg * 4 + i][r] = acc0[i];
        dots[wq][kg * 4 + i][16 + r] = acc1[i];
    }
    __syncthreads();

    if (tid < 16) {   // one thread per row: scalar epilogue
        float s = 0.f;
#pragma unroll
        for (int q = 0; q < 8; ++q) s += ssq_s[q][tid];
        float inv_rms = rsqrtf(s * (1.0f / 8192.0f) + 1.1920929e-7f);
        float pj[32];
#pragma unroll
        for (int j = 0; j < 32; ++j) {
            float d = 0.f;
#pragma unroll
            for (int q = 0; q < 8; ++q) d += dots[q][tid][j];
            pj[j] = d * inv_rms;
        }
        float ap = a_pre[0], apo = a_post[0], ar = a_res[0];
        float hpre[4], hpost[4];
#pragma unroll
        for (int n = 0; n < 4; ++n) {
            hpre[n] = 1.0f / (1.0f + expf(-(ap * pj[n] + b_all[n])));
            hpost[n] = 2.0f / (1.0f + expf(-(apo * pj[4 + n] + b_all[4 + n])));
        }
        float z[24]; float mx = -1e30f;
#pragma unroll
        for (int p = 0; p < 24; ++p) { z[p] = ar * pj[8 + p] + b_all[8 + p]; mx = fmaxf(mx, z[p]); }
        float se = 0.f;
#pragma unroll
        for (int p = 0; p < 24; ++p) { z[p] = expf(z[p] - mx); se += z[p]; }
        float isum = 1.0f / se;
        float Hr[16];
#pragma unroll
        for (int e = 0; e < 16; ++e) Hr[e] = 0.f;
#pragma unroll
        for (int p = 0; p < 24; ++p) {
            float a = z[p] * isum;
#pragma unroll
            for (int e = 0; e < 16; ++e) Hr[e] += a * perm[p * 16 + e];
        }
        float* P = params + (size_t)(brow + tid) * 24;
#pragma unroll
        for (int n = 0; n < 4; ++n) { P[n] = hpre[n]; P[4 + n] = hpost[n]; hpre_l[tid][n] = hpre[n]; }
#pragma unroll
        for (int n = 0; n < 4; ++n)
#pragma unroll
            for (int m = 0; m < 4; ++m)
                P[8 + n * 4 + m] = Hr[n * 4 + m] - hpost[n] * hpre[m];
    }
    __syncthreads();

    // layer_input phase: block's x rows just streamed -> L2/L3-warm
    const int c = tid * 4;
#pragma unroll 2
    for (int rr = 0; rr < 16; ++rr) {
        float h0 = hpre_l[rr][0], h1 = hpre_l[rr][1], h2 = hpre_l[rr][2], h3 = hpre_l[rr][3];
        const float* xr = x + (size_t)(brow + rr) * 8192 + c;
        float4 a0 = *(const float4*)(xr);
        float4 a1 = *(const float4*)(xr + 2048);
        float4 a2 = *(const float4*)(xr + 4096);
        float4 a3 = *(const float4*)(xr + 6144);
        ushort4 ob;
        ob.x = f2bf(h0 * a0.x + h1 * a1.x + h2 * a2.x + h3 * a3.x);
        ob.y = f2bf(h0 * a0.y + h1 * a1.y + h2 * a2.y + h3 * a3.y);
        ob.z = f2bf(h0 * a0.z + h1 * a1.z + h2 * a2.z + h3 * a3.z);
        ob.w = f2bf(h0 * a0.w + h1 * a1.w + h2 * a2.w + h3 * a3.w);
        *(ushort4*)(li + (size_t)(brow + rr) * 2048 + c) = ob;
    }
}

// ---------------- K3: GEMM (li @ W_layer^T) + fused final combine ----------------
// 128x128 tile, BK=64, 4 waves. 2-phase dbuf (round-3 k-loop, PASSED) with
// NATURAL block order (round-3's XCD swizzle doubled FETCH; round-2 natural
// order measured 207MB). 8-wave variant shelved: failed twice (r4/r5),
// suspected compiler hoist of global_load_lds across the publishing barrier.
__global__ __launch_bounds__(256) void k_gemm_out(
    const ushort* __restrict__ liA,    // [8192][2048] bf16
    const ushort* __restrict__ WB,     // [2048][2048] bf16 (c,k) = B^T layout
    const float* __restrict__ b_layer, // [2048]
    const float* __restrict__ params,  // [8192][24]
    const float* __restrict__ x,       // [8192][8192]
    float* __restrict__ out)           // [8192][4][2048]
{
    __shared__ ushort Alds[2][128 * 64];
    __shared__ ushort Blds[2][128 * 64];
    __shared__ float Plds[128 * 25];
    __shared__ float bl_s[128];

    const int tid = threadIdx.x;
    const int ln = tid & 63;
    const int wv = tid >> 6;
    const int brow = blockIdx.x * 128;
    const int bcol = blockIdx.y * 128;

    for (int i = tid; i < 128 * 24; i += 256) {
        int r = i / 24, j = i - r * 24;
        Plds[r * 25 + j] = params[(size_t)(brow + r) * 24 + j];
    }
    if (tid < 128) bl_s[tid] = b_layer[bcol + tid];

    f32x4 acc[4][4] = {};

    const int srow = ln >> 3;                       // staging row within 8-row group
    const int scol = ((ln & 7) ^ srow) * 8;         // pre-swizzled source col
    const int wm = wv >> 1, wn = wv & 1;
    const int fr = ln & 15, fq = ln >> 4;
    const int swz = (fr & 7) << 3;                  // read-side XOR (ushort units)

    auto do_stage = [&](int buf, int k0) {
#pragma unroll
        for (int q = 0; q < 4; ++q) {
            int row = wv * 32 + q * 8 + srow;
            stage16(liA + (size_t)(brow + row) * 2048 + k0 + scol, &Alds[buf][wv * 2048 + q * 512], ln);
            stage16(WB + (size_t)(bcol + row) * 2048 + k0 + scol, &Blds[buf][wv * 2048 + q * 512], ln);
        }
    };

    do_stage(0, 0);
    __syncthreads();

    int cur = 0;
    for (int k0 = 0; k0 < 2048; k0 += 64) {
        if (k0 + 64 < 2048) do_stage(cur ^ 1, k0 + 64);   // prefetch flies under MFMA
#pragma unroll
        for (int kk = 0; kk < 64; kk += 32) {
            bf16x8 af[4], bg[4];
#pragma unroll
            for (int mi = 0; mi < 4; ++mi)
                af[mi] = *(const bf16x8*)&Alds[cur][(wm * 64 + mi * 16 + fr) * 64 + ((kk + fq * 8) ^ swz)];
#pragma unroll
            for (int ni = 0; ni < 4; ++ni)
                bg[ni] = *(const bf16x8*)&Blds[cur][(wn * 64 + ni * 16 + fr) * 64 + ((kk + fq * 8) ^ swz)];
#pragma unroll
            for (int mi = 0; mi < 4; ++mi)
#pragma unroll
                for (int ni = 0; ni < 4; ++ni)
                    acc[mi][ni] = __builtin_amdgcn_mfma_f32_16x16x32_bf16(bg[ni], af[mi], acc[mi][ni], 0, 0, 0);
        }
        __syncthreads();         // one barrier per K-tile: drains prefetch + guards reuse
        cur ^= 1;
    }

    // Epilogue. Swapped operands: lane holds t=...+fr, c=...+fq*4+i -> float4 I/O.
    // out[t,n,c] = sum_m Hm[n,m]*x[t,m,c] + h_post[n]*(acc + b_layer[c])
#pragma unroll
    for (int mi = 0; mi < 4; ++mi) {
        const int t_loc = wm * 64 + mi * 16 + fr;
        const size_t t = (size_t)(brow + t_loc);
        const float* P = &Plds[t_loc * 25];
        float hp0 = P[4], hp1 = P[5], hp2 = P[6], hp3 = P[7];
        float Hm[16];
#pragma unroll
        for (int e = 0; e < 16; ++e) Hm[e] = P[8 + e];
        const float* xt = x + t * 8192;
        float* ot = out + t * 8192;
#pragma unroll
        for (int ni = 0; ni < 4; ++ni) {
            const int c_loc = wn * 64 + ni * 16 + fq * 4;
            const int cg = bcol + c_loc;
            float4 bl = *(const float4*)&bl_s[c_loc];
            float4 x0 = *(const float4*)(xt + cg);
            float4 x1 = *(const float4*)(xt + 2048 + cg);
            float4 x2 = *(const float4*)(xt + 4096 + cg);
            float4 x3 = *(const float4*)(xt + 6144 + cg);
            float4 lo;
            lo.x = acc[mi][ni][0] + bl.x;
            lo.y = acc[mi][ni][1] + bl.y;
            lo.z = acc[mi][ni][2] + bl.z;
            lo.w = acc[mi][ni][3] + bl.w;
            float hp[4] = {hp0, hp1, hp2, hp3};
#pragma unroll
            for (int n = 0; n < 4; ++n) {
                float4 v;
                v.x = hp[n] * lo.x + Hm[n*4+0] * x0.x + Hm[n*4+1] * x1.x + Hm[n*4+2] * x2.x + Hm[n*4+3] * x3.x;
                v.y = hp[n] * lo.y + Hm[n*4+0] * x0.y + Hm[n*4+1] * x1.y + Hm[n*4+2] * x2.y + Hm[n*4+3] * x3.y;
                v.z = hp[n] * lo.z + Hm[n*4+0] * x0.z + Hm[n*4+1] * x1.z + Hm[n*4+2] * x2.z + Hm[n*4+3] * x3.z;
                v.w = hp[n] * lo.w + Hm[n*4+0] * x0.w + Hm[n*4+1] * x1.w + Hm[n*4+2] * x2.w + Hm[n*4+3] * x3.w;
                *(float4*)(ot + (size_t)n * 2048 + cg) = v;
            }
        }
    }
}

extern "C" void kernel_launch(void* const* d_in, const int* in_sizes, int n_in,
                              void* d_out, int out_size, void* d_ws, size_t ws_size,
                              hipStream_t stream) {
    const float* x       = (const float*)d_in[0];
    const float* W_all   = (const float*)d_in[1];
    const float* b_all   = (const float*)d_in[2];
    const float* a_pre   = (const float*)d_in[3];
    const float* a_post  = (const float*)d_in[4];
    const float* a_res   = (const float*)d_in[5];
    const float* perm    = (const float*)d_in[6];
    const float* W_layer = (const float*)d_in[7];
    const float* b_layer = (const float*)d_in[8];
    float* out = (float*)d_out;

    char* ws = (char*)d_ws;
    ushort* wall_b   = (ushort*)(ws);                                        // 512 KB
    ushort* wlayer_b = (ushort*)(ws + (512u << 10));                         // 8 MB
    float*  params   = (float*)(ws + (512u << 10) + (8u << 20));             // 768 KB
    ushort* li       = (ushort*)(ws + (512u << 10) + (8u << 20) + (768u << 10)); // 32 MB

    k_cvt<<<dim3(256), dim3(256), 0, stream>>>(W_all, wall_b, 65536);
    k_cvt<<<dim3(4096), dim3(256), 0, stream>>>(W_layer, wlayer_b, 1048576);
    k_stats<<<dim3(512), dim3(512), 0, stream>>>(x, wall_b, b_all, a_pre, a_post, a_res,
                                                 perm, params, li);
    k_gemm_out<<<dim3(64, 16), dim3(256), 0, stream>>>(li, wlayer_b, b_layer, params, x, out);
}

// Round 7
// 335.681 us; speedup vs baseline: 1.6354x; 1.0832x over previous
//
#include <hip/hip_runtime.h>

typedef __attribute__((ext_vector_type(8))) short bf16x8;
typedef __attribute__((ext_vector_type(4))) float f32x4;

#if defined(__has_builtin)
#if __has_builtin(__builtin_amdgcn_global_load_lds)
#define HAVE_GLL 1
#endif
#endif

__device__ __forceinline__ ushort f2bf(float f) {
    unsigned u = __float_as_uint(f);
    u += 0x7fffu + ((u >> 16) & 1u);   // round-to-nearest-even
    return (ushort)(u >> 16);
}

// global->LDS 16B stage. GLL path: lbase is wave-uniform, HW adds lane*16.
__device__ __forceinline__ void stage16(const ushort* __restrict__ g, ushort* lbase, int lane) {
#ifdef HAVE_GLL
    __builtin_amdgcn_global_load_lds((const __attribute__((address_space(1))) void*)g,
                                     (__attribute__((address_space(3))) void*)lbase,
                                     16, 0, 0);
#else
    *(float4*)(lbase + lane * 8) = *(const float4*)g;
#endif
}

// ---------------- K0: f32 -> bf16 weight conversion ----------------
__global__ void k_cvt(const float* __restrict__ src, ushort* __restrict__ dst, int n4) {
    int i = blockIdx.x * blockDim.x + threadIdx.x;
    if (i >= n4) return;
    float4 v = ((const float4*)src)[i];
    ushort4 o;
    o.x = f2bf(v.x); o.y = f2bf(v.y); o.z = f2bf(v.z); o.w = f2bf(v.w);
    ((ushort4*)dst)[i] = o;
}

// ---------------- K1: per-row stats + params + layer_input ----------------
// 512 blocks x 512 threads (8 waves). 16 rows/block; wave wq owns k-eighth.
// MFMA A/B fragments built DIRECTLY in registers (no LDS staging, no
// barriers in the k-loop). dot(x_norm,w) = inv_rms*dot(x,w).
__global__ __launch_bounds__(512) void k_stats(
    const float* __restrict__ x,        // [8192][8192]
    const ushort* __restrict__ wallb,   // [32][8192] bf16
    const float* __restrict__ b_all,    // [32]
    const float* __restrict__ a_pre, const float* __restrict__ a_post,
    const float* __restrict__ a_res,
    const float* __restrict__ perm,     // [24][16]
    float* __restrict__ params,         // [8192][24]: h_pre[4] h_post[4] Hm[16]
    ushort* __restrict__ li)            // [8192][2048] bf16
{
    __shared__ float dots[8][16][33];
    __shared__ float ssq_s[8][16];
    __shared__ float hpre_l[16][4];

    const int tid = threadIdx.x;
    const int lane = tid & 63;
    const int wq = tid >> 6;            // k-eighth 0..7
    const int r = lane & 15;            // x-row / W-row within group
    const int kg = lane >> 4;           // k-subgroup 0..3
    const int brow = blockIdx.x * 16;

    const float* xp = x + (size_t)(brow + r) * 8192 + wq * 1024 + kg * 8;
    const ushort* wp0 = wallb + (size_t)r * 8192 + wq * 1024 + kg * 8;
    const ushort* wp1 = wp0 + 16 * 8192;

    f32x4 acc0 = {}, acc1 = {};
    float ssq = 0.f;

#pragma unroll 4
    for (int s = 0; s < 32; ++s) {
        const int off = s * 32;
        float4 a0 = *(const float4*)(xp + off);
        float4 a1 = *(const float4*)(xp + off + 4);
        float va[8] = {a0.x, a0.y, a0.z, a0.w, a1.x, a1.y, a1.z, a1.w};
        union { ushort u[8]; bf16x8 v; } av;
#pragma unroll
        for (int j = 0; j < 8; ++j) { ssq += va[j] * va[j]; av.u[j] = f2bf(va[j]); }
        bf16x8 b0 = *(const bf16x8*)(wp0 + off);
        bf16x8 b1 = *(const bf16x8*)(wp1 + off);
        acc0 = __builtin_amdgcn_mfma_f32_16x16x32_bf16(av.v, b0, acc0, 0, 0, 0);
        acc1 = __builtin_amdgcn_mfma_f32_16x16x32_bf16(av.v, b1, acc1, 0, 0, 0);
    }

    // ssq: reduce over the 4 kg-groups holding the same row
    ssq += __shfl_xor(ssq, 16);
    ssq += __shfl_xor(ssq, 32);
    if (lane < 16) ssq_s[wq][r] = ssq;
    // D layout: row=(lane>>4)*4+i (x-row), col=lane&15 (j)
#pragma unroll
    for (int i = 0; i < 4; ++i) {
        dots[wq][kg * 4 + i][r] = acc0[i];
        dots[wq][kg * 4 + i][16 + r] = acc1[i];
    }
    __syncthreads();

    if (tid < 16) {   // one thread per row: scalar epilogue
        float s = 0.f;
#pragma unroll
        for (int q = 0; q < 8; ++q) s += ssq_s[q][tid];
        float inv_rms = rsqrtf(s * (1.0f / 8192.0f) + 1.1920929e-7f);
        float pj[32];
#pragma unroll
        for (int j = 0; j < 32; ++j) {
            float d = 0.f;
#pragma unroll
            for (int q = 0; q < 8; ++q) d += dots[q][tid][j];
            pj[j] = d * inv_rms;
        }
        float ap = a_pre[0], apo = a_post[0], ar = a_res[0];
        float hpre[4], hpost[4];
#pragma unroll
        for (int n = 0; n < 4; ++n) {
            hpre[n] = 1.0f / (1.0f + expf(-(ap * pj[n] + b_all[n])));
            hpost[n] = 2.0f / (1.0f + expf(-(apo * pj[4 + n] + b_all[4 + n])));
        }
        float z[24]; float mx = -1e30f;
#pragma unroll
        for (int p = 0; p < 24; ++p) { z[p] = ar * pj[8 + p] + b_all[8 + p]; mx = fmaxf(mx, z[p]); }
        float se = 0.f;
#pragma unroll
        for (int p = 0; p < 24; ++p) { z[p] = expf(z[p] - mx); se += z[p]; }
        float isum = 1.0f / se;
        float Hr[16];
#pragma unroll
        for (int e = 0; e < 16; ++e) Hr[e] = 0.f;
#pragma unroll
        for (int p = 0; p < 24; ++p) {
            float a = z[p] * isum;
#pragma unroll
            for (int e = 0; e < 16; ++e) Hr[e] += a * perm[p * 16 + e];
        }
        float* P = params + (size_t)(brow + tid) * 24;
#pragma unroll
        for (int n = 0; n < 4; ++n) { P[n] = hpre[n]; P[4 + n] = hpost[n]; hpre_l[tid][n] = hpre[n]; }
#pragma unroll
        for (int n = 0; n < 4; ++n)
#pragma unroll
            for (int m = 0; m < 4; ++m)
                P[8 + n * 4 + m] = Hr[n * 4 + m] - hpost[n] * hpre[m];
    }
    __syncthreads();

    // layer_input phase: block's x rows just streamed -> L2/L3-warm
    const int c = tid * 4;
#pragma unroll 2
    for (int rr = 0; rr < 16; ++rr) {
        float h0 = hpre_l[rr][0], h1 = hpre_l[rr][1], h2 = hpre_l[rr][2], h3 = hpre_l[rr][3];
        const float* xr = x + (size_t)(brow + rr) * 8192 + c;
        float4 a0 = *(const float4*)(xr);
        float4 a1 = *(const float4*)(xr + 2048);
        float4 a2 = *(const float4*)(xr + 4096);
        float4 a3 = *(const float4*)(xr + 6144);
        ushort4 ob;
        ob.x = f2bf(h0 * a0.x + h1 * a1.x + h2 * a2.x + h3 * a3.x);
        ob.y = f2bf(h0 * a0.y + h1 * a1.y + h2 * a2.y + h3 * a3.y);
        ob.z = f2bf(h0 * a0.z + h1 * a1.z + h2 * a2.z + h3 * a3.z);
        ob.w = f2bf(h0 * a0.w + h1 * a1.w + h2 * a2.w + h3 * a3.w);
        *(ushort4*)(li + (size_t)(brow + rr) * 2048 + c) = ob;
    }
}

// ---------------- K3: GEMM (li @ W_layer^T) + fused final combine ----------------
// 128x128 tile, BK=64, 4 waves, 2-phase dbuf (round-6 mainloop, PASSED,
// byte-identical). NEW: coalesced LDS-roundtrip epilogue — acc+bias staged
// into a 64KB f32 lo[128][128] (reusing the A/B dbuf space), then streamed
// with lanes 0-31 = 128 consecutive floats of row r, lanes 32-63 = row r+1:
// every x-load / out-store is 2x512B contiguous segments (was 16x16B scatter
// across 16 rows per instruction).
__global__ __launch_bounds__(256) void k_gemm_out(
    const ushort* __restrict__ liA,    // [8192][2048] bf16
    const ushort* __restrict__ WB,     // [2048][2048] bf16 (c,k) = B^T layout
    const float* __restrict__ b_layer, // [2048]
    const float* __restrict__ params,  // [8192][24]
    const float* __restrict__ x,       // [8192][8192]
    float* __restrict__ out)           // [8192][4][2048]
{
    __shared__ __align__(16) ushort ABlds[4][128 * 64];  // A=buf 0/1, B=buf 2/3; 64KB
    __shared__ float Plds[128 * 25];
    __shared__ float bl_s[128];

    const int tid = threadIdx.x;
    const int ln = tid & 63;
    const int wv = tid >> 6;
    const int brow = blockIdx.x * 128;
    const int bcol = blockIdx.y * 128;

    for (int i = tid; i < 128 * 24; i += 256) {
        int r = i / 24, j = i - r * 24;
        Plds[r * 25 + j] = params[(size_t)(brow + r) * 24 + j];
    }
    if (tid < 128) bl_s[tid] = b_layer[bcol + tid];

    f32x4 acc[4][4] = {};

    const int srow = ln >> 3;                       // staging row within 8-row group
    const int scol = ((ln & 7) ^ srow) * 8;         // pre-swizzled source col
    const int wm = wv >> 1, wn = wv & 1;
    const int fr = ln & 15, fq = ln >> 4;
    const int swz = (fr & 7) << 3;                  // read-side XOR (ushort units)

    auto do_stage = [&](int buf, int k0) {
#pragma unroll
        for (int q = 0; q < 4; ++q) {
            int row = wv * 32 + q * 8 + srow;
            stage16(liA + (size_t)(brow + row) * 2048 + k0 + scol, &ABlds[buf][wv * 2048 + q * 512], ln);
            stage16(WB + (size_t)(bcol + row) * 2048 + k0 + scol, &ABlds[2 + buf][wv * 2048 + q * 512], ln);
        }
    };

    do_stage(0, 0);
    __syncthreads();

    int cur = 0;
    for (int k0 = 0; k0 < 2048; k0 += 64) {
        if (k0 + 64 < 2048) do_stage(cur ^ 1, k0 + 64);   // prefetch flies under MFMA
#pragma unroll
        for (int kk = 0; kk < 64; kk += 32) {
            bf16x8 af[4], bg[4];
#pragma unroll
            for (int mi = 0; mi < 4; ++mi)
                af[mi] = *(const bf16x8*)&ABlds[cur][(wm * 64 + mi * 16 + fr) * 64 + ((kk + fq * 8) ^ swz)];
#pragma unroll
            for (int ni = 0; ni < 4; ++ni)
                bg[ni] = *(const bf16x8*)&ABlds[2 + cur][(wn * 64 + ni * 16 + fr) * 64 + ((kk + fq * 8) ^ swz)];
#pragma unroll
            for (int mi = 0; mi < 4; ++mi)
#pragma unroll
                for (int ni = 0; ni < 4; ++ni)
                    acc[mi][ni] = __builtin_amdgcn_mfma_f32_16x16x32_bf16(bg[ni], af[mi], acc[mi][ni], 0, 0, 0);
        }
        __syncthreads();         // one barrier per K-tile: drains prefetch + guards reuse
        cur ^= 1;
    }

    // ---- Epilogue phase 1: acc + bias -> lo_lds[128][128] (f32, 64KB) ----
    float* lo_lds = (float*)&ABlds[0][0];
#pragma unroll
    for (int mi = 0; mi < 4; ++mi) {
#pragma unroll
        for (int ni = 0; ni < 4; ++ni) {
            const int t_loc = wm * 64 + mi * 16 + fr;
            const int c_loc = wn * 64 + ni * 16 + fq * 4;
            float4 bl = *(const float4*)&bl_s[c_loc];
            float4 v;
            v.x = acc[mi][ni][0] + bl.x;
            v.y = acc[mi][ni][1] + bl.y;
            v.z = acc[mi][ni][2] + bl.z;
            v.w = acc[mi][ni][3] + bl.w;
            *(float4*)&lo_lds[t_loc * 128 + c_loc] = v;
        }
    }
    __syncthreads();

    // ---- Epilogue phase 2: coalesced streaming combine ----
    // wave wv owns rows [wv*32, wv*32+32); lanes 0-31 -> row r, 32-63 -> r+1.
    // out[t,n,c] = sum_m Hm[n,m]*x[t,m,c] + h_post[n]*lo[t,c]
    const int half = ln >> 5;
    const int cl = (ln & 31) * 4;
    for (int rr = 0; rr < 32; rr += 2) {
        const int t_loc = wv * 32 + rr + half;
        const size_t t = (size_t)(brow + t_loc);
        float4 lo4 = *(const float4*)&lo_lds[t_loc * 128 + cl];
        const float* P = &Plds[t_loc * 25];
        const float* xt = x + t * 8192 + bcol + cl;
        float* ot = out + t * 8192 + bcol + cl;
        float4 x0 = *(const float4*)(xt);
        float4 x1 = *(const float4*)(xt + 2048);
        float4 x2 = *(const float4*)(xt + 4096);
        float4 x3 = *(const float4*)(xt + 6144);
#pragma unroll
        for (int n = 0; n < 4; ++n) {
            float hp = P[4 + n];
            float h0 = P[8 + n * 4 + 0], h1 = P[8 + n * 4 + 1];
            float h2 = P[8 + n * 4 + 2], h3 = P[8 + n * 4 + 3];
            float4 v;
            v.x = hp * lo4.x + h0 * x0.x + h1 * x1.x + h2 * x2.x + h3 * x3.x;
            v.y = hp * lo4.y + h0 * x0.y + h1 * x1.y + h2 * x2.y + h3 * x3.y;
            v.z = hp * lo4.z + h0 * x0.z + h1 * x1.z + h2 * x2.z + h3 * x3.z;
            v.w = hp * lo4.w + h0 * x0.w + h1 * x1.w + h2 * x2.w + h3 * x3.w;
            *(float4*)(ot + (size_t)n * 2048) = v;
        }
    }
}

extern "C" void kernel_launch(void* const* d_in, const int* in_sizes, int n_in,
                              void* d_out, int out_size, void* d_ws, size_t ws_size,
                              hipStream_t stream) {
    const float* x       = (const float*)d_in[0];
    const float* W_all   = (const float*)d_in[1];
    const float* b_all   = (const float*)d_in[2];
    const float* a_pre   = (const float*)d_in[3];
    const float* a_post  = (const float*)d_in[4];
    const float* a_res   = (const float*)d_in[5];
    const float* perm    = (const float*)d_in[6];
    const float* W_layer = (const float*)d_in[7];
    const float* b_layer = (const float*)d_in[8];
    float* out = (float*)d_out;

    char* ws = (char*)d_ws;
    ushort* wall_b   = (ushort*)(ws);                                        // 512 KB
    ushort* wlayer_b = (ushort*)(ws + (512u << 10));                         // 8 MB
    float*  params   = (float*)(ws + (512u << 10) + (8u << 20));             // 768 KB
    ushort* li       = (ushort*)(ws + (512u << 10) + (8u << 20) + (768u << 10)); // 32 MB

    k_cvt<<<dim3(256), dim3(256), 0, stream>>>(W_all, wall_b, 65536);
    k_cvt<<<dim3(4096), dim3(256), 0, stream>>>(W_layer, wlayer_b, 1048576);
    k_stats<<<dim3(512), dim3(512), 0, stream>>>(x, wall_b, b_all, a_pre, a_post, a_res,
                                                 perm, params, li);
    k_gemm_out<<<dim3(64, 16), dim3(256), 0, stream>>>(li, wlayer_b, b_layer, params, x, out);
}